// Round 6
// baseline (64.101 us; speedup 1.0000x reference)
//
#include <hip/hip_runtime.h>
#include <math.h>

#define BATCH 256
#define CIN   3
#define COUT  16
#define DI    16
#define HI    32
#define WI    32

typedef _Float16 f16;
typedef f16   f16x4 __attribute__((ext_vector_type(4)));
typedef f16   f16x8 __attribute__((ext_vector_type(8)));
typedef float f32x4 __attribute__((ext_vector_type(4)));

// LDS slab (f16 units): xs[dd][hh][w][ci], ci stride 1 (3 cin + pad),
// w slots 0..35 (32 data + 4 zero pad), row stride ROWU=144 (288B),
// plane stride PLANEU=4320. 288B ≡ 32 mod 128 -> spread banks.
#define ROWU   144
#define PLANEU 4320
#define XS_N   (6 * PLANEU)              // 51840 B -> 3 WG/CU
#define G8OFF  (2 * PLANEU + 2 * ROWU)   // (kd=2,kh=2) row offset

#define SV8(a, b) __builtin_shufflevector(a, b, 0, 1, 2, 3, 4, 5, 6, 7)
#define MFMA16(A, B, C) __builtin_amdgcn_mfma_f32_16x16x32_f16(A, B, C, 0, 0, 0)

// One fused (group,d,hl) step: 8 ds_read_b64 (imm offsets) + 4 MFMA +
// softmax over couts (q-sum via xor16/32) + per-lane pool accumulate.
#define ITER(pmv, D, HL, SPAT)  do {                                          \
    const f16* rb_ = xs + (D) * PLANEU + (HL) * ROWU + (SPAT);                \
    f16x4 b10_ = *(const f16x4*)(rb_ + off1);                                 \
    f16x4 b20_ = *(const f16x4*)(rb_ + off2);                                 \
    f16x4 b11_ = *(const f16x4*)(rb_ + off1 + 4);                             \
    f16x4 b21_ = *(const f16x4*)(rb_ + off2 + 4);                             \
    f16x4 b12_ = *(const f16x4*)(rb_ + off1 + 8);                             \
    f16x4 b22_ = *(const f16x4*)(rb_ + off2 + 8);                             \
    f16x4 ga_  = *(const f16x4*)(rb_ + G8OFF + g8sel);                        \
    f16x4 gb_  = *(const f16x4*)(rb_ + G8OFF + g8sel + 4);                    \
    f32x4 a_ = {0.f, 0.f, 0.f, 0.f};                                          \
    a_ = MFMA16(wm[0], SV8(b10_, b20_), a_);                                  \
    a_ = MFMA16(wm[1], SV8(b11_, b21_), a_);                                  \
    a_ = MFMA16(wm[2], SV8(b12_, b22_), a_);                                  \
    a_ = MFMA16(wg,    SV8(ga_,  gb_),  a_);                                  \
    float y0_ = a_[0] + bv.x, y1_ = a_[1] + bv.y;                             \
    float y2_ = a_[2] + bv.z, y3_ = a_[3] + bv.w;                             \
    float e0_ = __expf(y0_), e1_ = __expf(y1_);                               \
    float e2_ = __expf(y2_), e3_ = __expf(y3_);                               \
    float s_ = (e0_ + e1_) + (e2_ + e3_);                                     \
    s_ += __shfl_xor(s_, 16);                                                 \
    s_ += __shfl_xor(s_, 32);                                                 \
    float inv_ = __builtin_amdgcn_rcpf(s_);                                   \
    pmv[0] = fmaxf(pmv[0], e0_ * inv_);                                       \
    pmv[1] = fmaxf(pmv[1], e1_ * inv_);                                       \
    pmv[2] = fmaxf(pmv[2], e2_ * inv_);                                       \
    pmv[3] = fmaxf(pmv[3], e3_ * inv_);                                       \
} while (0)

// ---------------------------------------------------------------------------
// Fused conv3d + bias + channel-softmax + 4^3 maxpool.
// One WG per (b,pd); 768 WGs = 3 WG/CU, whole grid resident.
// MFMA cols = 4 cells (2ch x 2pw) x 4 wl -> pool over (hl,d) in registers,
// only xor1/2 (DPP) pool + xor16/32 cout-sum shuffles remain.
// Staging split: dd0-2 before barrier#1; dd3-5 loads issued after barrier#1,
// HBM latency hidden under d=0 compute (disjoint LDS region), barrier#2.
// ---------------------------------------------------------------------------
__global__ __launch_bounds__(256, 3) void conv_sm_pool_mfma(
    const float* __restrict__ x, const float* __restrict__ W,
    const float* __restrict__ bias, float* __restrict__ out)
{
    __shared__ __align__(16) f16 xs[XS_N];

    const int tid  = threadIdx.x;
    const int lane = tid & 63;
    const int wave = tid >> 6;
    const int b    = blockIdx.x / 3;
    const int pd   = blockIdx.x % 3;
    const int d0   = pd * 4;

    const int col = lane & 15;     // MFMA column: cc*8 + ww*4 + wl
    const int q   = lane >> 4;     // K-slot group

    // ---- W gather -> A-fragments (k = g*4 + ci, g = kd*3+kh) ----
    const float* wc  = W + col * 81;
    const float* wqp = wc + q * 6;
    f16x8 wm[3];
    #pragma unroll
    for (int kw = 0; kw < 3; ++kw) {
        #pragma unroll
        for (int j = 0; j < 8; ++j) {
            const int ci = j & 3, jj = j >> 2;
            float v = (ci < 3) ? wqp[ci * 27 + 3 * jj + kw] : 0.f;
            wm[kw][j] = (f16)v;
        }
    }
    f16x8 wg = {};
    if (q == 0) {
        #pragma unroll
        for (int j = 0; j < 8; ++j) {
            const int ci = j & 3, kw = j >> 2;
            if (ci < 3) wg[j] = (f16)wc[ci * 27 + 24 + kw];
        }
    } else if (q == 1) {
        #pragma unroll
        for (int j = 0; j < 3; ++j) wg[j] = (f16)wc[j * 27 + 26];
    }
    const float4 bv = *(const float4*)(bias + q * 4);   // couts 4q+0..3

    // ---- A1: stage planes dd=0..2 (f16, cin-interleaved) ----
    for (int i = tid; i < 720; i += 256) {               // 3 dd * 30 hh * 8 wq
        int wqd = i & 7;
        int r   = i >> 3;
        int hh  = r % 30;
        int dd  = r / 30;
        const float* px = x + ((size_t)b * 48 + (d0 + dd)) * 1024 + hh * 32 + wqd * 4;
        float4 a0 = *(const float4*)(px);
        float4 a1 = *(const float4*)(px + 16384);
        float4 a2 = *(const float4*)(px + 32768);
        f16x8 p0, p1;
        p0[0] = (f16)a0.x; p0[1] = (f16)a1.x; p0[2] = (f16)a2.x; p0[3] = (f16)0.f;
        p0[4] = (f16)a0.y; p0[5] = (f16)a1.y; p0[6] = (f16)a2.y; p0[7] = (f16)0.f;
        p1[0] = (f16)a0.z; p1[1] = (f16)a1.z; p1[2] = (f16)a2.z; p1[3] = (f16)0.f;
        p1[4] = (f16)a0.w; p1[5] = (f16)a1.w; p1[6] = (f16)a2.w; p1[7] = (f16)0.f;
        f16* dst = xs + ((dd * 30 + hh) * 36 + wqd * 4) * 4;
        *(f16x8*)(dst)     = p0;
        *(f16x8*)(dst + 8) = p1;
    }
    // zero the w-pad (w=32..35) of ALL 180 rows (pw=7 garbage columns read it)
    if (tid < 180) {
        f16x8 z = {};
        f16* pz = xs + tid * ROWU + 128;
        *(f16x8*)(pz)     = z;
        *(f16x8*)(pz + 8) = z;
    }

    // ---- per-lane invariants ----
    const int g0   = q * 2;
    const int off1 = (g0 / 3) * PLANEU + (g0 % 3) * ROWU;
    const int off2 = ((g0 + 1) / 3) * PLANEU + ((g0 + 1) % 3) * ROWU;
    const int cc = (col >> 3) & 1;
    const int ww = (col >> 2) & 1;
    const int wl = col & 3;
    const int g8sel = (q == 0) ? 0 : 8;
    const int pw  = 2 * wave + ww;                 // 0..7 (7 = discarded pad)
    const int wb4 = (pw * 4 + wl) * 4;
    int spati[4];
    #pragma unroll
    for (int i = 0; i < 4; ++i) {
        int ch = 2 * i + cc;                       // 0..7; clamp 7 -> 6 (dup, discarded)
        if (ch > 6) ch = 6;
        spati[i] = ch * 4 * ROWU + wb4;
    }

    __syncthreads();   // barrier #1: dd0-2 staged

    // ---- A2 issue: planes dd=3..5 -> regs (latency hides under d=0) ----
    float4 ra0[3], ra1[3], ra2[3];
    #pragma unroll
    for (int j = 0; j < 3; ++j) {
        int t = tid + 256 * j;
        if (t < 720) {
            int wqd = t & 7, r = t >> 3;
            int hh = r % 30, dd = 3 + r / 30;
            const float* px = x + ((size_t)b * 48 + (d0 + dd)) * 1024 + hh * 32 + wqd * 4;
            ra0[j] = *(const float4*)(px);
            ra1[j] = *(const float4*)(px + 16384);
            ra2[j] = *(const float4*)(px + 32768);
        }
    }

    f32x4 pm[4];
    #pragma unroll
    for (int i = 0; i < 4; ++i) pm[i] = (f32x4){0.f, 0.f, 0.f, 0.f};

    // ---- d=0 compute (needs only dd 0..2) ----
    #pragma unroll
    for (int i = 0; i < 4; ++i) {
        #pragma unroll
        for (int hl = 0; hl < 4; ++hl) ITER(pm[i], 0, hl, spati[i]);
    }

    // ---- A2 convert + LDS write (disjoint region; vmcnt waits land here) ----
    #pragma unroll
    for (int j = 0; j < 3; ++j) {
        int t = tid + 256 * j;
        if (t < 720) {
            int wqd = t & 7, r = t >> 3;
            int hh = r % 30, dd = 3 + r / 30;
            f16x8 p0, p1;
            p0[0] = (f16)ra0[j].x; p0[1] = (f16)ra1[j].x; p0[2] = (f16)ra2[j].x; p0[3] = (f16)0.f;
            p0[4] = (f16)ra0[j].y; p0[5] = (f16)ra1[j].y; p0[6] = (f16)ra2[j].y; p0[7] = (f16)0.f;
            p1[0] = (f16)ra0[j].z; p1[1] = (f16)ra1[j].z; p1[2] = (f16)ra2[j].z; p1[3] = (f16)0.f;
            p1[4] = (f16)ra0[j].w; p1[5] = (f16)ra1[j].w; p1[6] = (f16)ra2[j].w; p1[7] = (f16)0.f;
            f16* dst = xs + ((dd * 30 + hh) * 36 + wqd * 4) * 4;
            *(f16x8*)(dst)     = p0;
            *(f16x8*)(dst + 8) = p1;
        }
    }
    __syncthreads();   // barrier #2: dd3-5 staged

    // ---- d=1..3 compute ----
    #pragma unroll
    for (int i = 0; i < 4; ++i) {
        #pragma unroll
        for (int d = 1; d < 4; ++d) {
            #pragma unroll
            for (int hl = 0; hl < 4; ++hl) ITER(pm[i], d, hl, spati[i]);
        }
    }

    // ---- epilogue: pool over wl (DPP xor1/2), store valid cells ----
    #pragma unroll
    for (int i = 0; i < 4; ++i) {
        #pragma unroll
        for (int r = 0; r < 4; ++r) {
            float v = pm[i][r];
            v = fmaxf(v, __shfl_xor(v, 1));
            v = fmaxf(v, __shfl_xor(v, 2));
            pm[i][r] = v;
        }
        const int ch = 2 * i + cc;
        if (wl == 0 && ch < 7 && pw < 7) {
            float* po = out + ((size_t)b * COUT + q * 4) * 147 + pd * 49 + ch * 7 + pw;
            po[0]   = pm[i][0];
            po[147] = pm[i][1];
            po[294] = pm[i][2];
            po[441] = pm[i][3];
        }
    }
}

extern "C" void kernel_launch(void* const* d_in, const int* in_sizes, int n_in,
                              void* d_out, int out_size, void* d_ws, size_t ws_size,
                              hipStream_t stream) {
    const float* x    = (const float*)d_in[0];
    const float* W    = (const float*)d_in[1];
    const float* bias = (const float*)d_in[2];
    float* out = (float*)d_out;

    conv_sm_pool_mfma<<<BATCH * 3, 256, 0, stream>>>(x, W, bias, out);
}

// Round 7
// 37.125 us; speedup vs baseline: 1.7266x; 1.7266x over previous
//
#include <hip/hip_runtime.h>
#include <math.h>

#define BATCH 256
#define CIN   3
#define COUT  16
#define DI    16
#define HI    32
#define WI    32

typedef _Float16 f16;
typedef f16   f16x4 __attribute__((ext_vector_type(4)));
typedef f16   f16x8 __attribute__((ext_vector_type(8)));
typedef float f32x4 __attribute__((ext_vector_type(4)));

// LDS slab (f16 units): xs[dd][hh][w][ci], ci stride 1 (3 cin + pad),
// w stride 4, row stride ROWU=144 (288B), plane stride PLANEU=4320.
// 288B row ≡ 32 mod 128 -> B-read bank pattern spread, <=2-way (free).
#define ROWU   144
#define PLANEU 4320
#define XS_N   (6 * PLANEU)              // 51840 B -> 3 WG/CU
#define G8OFF  (2 * PLANEU + 2 * ROWU)   // (kd=2,kh=2) row offset

#define SV8(a, b) __builtin_shufflevector(a, b, 0, 1, 2, 3, 4, 5, 6, 7)
#define MFMA16(A, B, C) __builtin_amdgcn_mfma_f32_16x16x32_f16(A, B, C, 0, 0, 0)

// One (cell,d) step: 8 ds_read_b64 + 4-chain MFMA + softmax + pool-max accumulate.
// Two of these back-to-back (pair of cells) give 2 independent dataflow chains.
#define CELLD(rb, pmv)  do {                                                  \
    const f16* rb_ = (rb);                                                    \
    f16x4 b10_ = *(const f16x4*)(rb_ + off1);                                 \
    f16x4 b20_ = *(const f16x4*)(rb_ + off2);                                 \
    f16x4 b11_ = *(const f16x4*)(rb_ + off1 + 4);                             \
    f16x4 b21_ = *(const f16x4*)(rb_ + off2 + 4);                             \
    f16x4 b12_ = *(const f16x4*)(rb_ + off1 + 8);                             \
    f16x4 b22_ = *(const f16x4*)(rb_ + off2 + 8);                             \
    f16x4 ga_  = *(const f16x4*)(rb_ + G8OFF + g8sel);                        \
    f16x4 gb_  = *(const f16x4*)(rb_ + G8OFF + g8sel + 4);                    \
    f32x4 a_ = {0.f, 0.f, 0.f, 0.f};                                          \
    a_ = MFMA16(wm[0], SV8(b10_, b20_), a_);                                  \
    a_ = MFMA16(wm[1], SV8(b11_, b21_), a_);                                  \
    a_ = MFMA16(wm[2], SV8(b12_, b22_), a_);                                  \
    a_ = MFMA16(wg,    SV8(ga_,  gb_),  a_);                                  \
    float y0_ = a_[0] + bv.x, y1_ = a_[1] + bv.y;                             \
    float y2_ = a_[2] + bv.z, y3_ = a_[3] + bv.w;                             \
    float e0_ = __expf(y0_), e1_ = __expf(y1_);                               \
    float e2_ = __expf(y2_), e3_ = __expf(y3_);                               \
    float s_ = (e0_ + e1_) + (e2_ + e3_);                                     \
    s_ += __shfl_xor(s_, 16);                                                 \
    s_ += __shfl_xor(s_, 32);                                                 \
    float inv_ = __builtin_amdgcn_rcpf(s_);                                   \
    pmv[0] = fmaxf(pmv[0], e0_ * inv_);                                       \
    pmv[1] = fmaxf(pmv[1], e1_ * inv_);                                       \
    pmv[2] = fmaxf(pmv[2], e2_ * inv_);                                       \
    pmv[3] = fmaxf(pmv[3], e3_ * inv_);                                       \
} while (0)

// ---------------------------------------------------------------------------
// Fused conv3d + bias + channel-softmax + 4^3 maxpool.
// One WG per (b,pd); 768 WGs = 3 WG/CU, whole grid resident, ONE barrier.
// Each wave owns complete pool cells; cells processed in PAIRS for 2x ILP
// (two independent MFMA chains + two independent softmax/shuffle chains).
// ---------------------------------------------------------------------------
__global__ __launch_bounds__(256, 3) void conv_sm_pool_mfma(
    const float* __restrict__ x, const float* __restrict__ W,
    const float* __restrict__ bias, float* __restrict__ out)
{
    __shared__ __align__(16) f16 xs[XS_N];

    const int tid  = threadIdx.x;
    const int lane = tid & 63;
    const int wave = tid >> 6;
    const int b    = blockIdx.x / 3;
    const int pd   = blockIdx.x % 3;
    const int d0   = pd * 4;

    const int col = lane & 15;     // MFMA column = position in cell (hl*4+wl)
    const int q   = lane >> 4;     // K-slot group

    // ---- W gather -> A-fragments (k = g*4 + ci, g = kd*3+kh; groups 2q,2q+1) ----
    const float* wc  = W + col * 81;
    const float* wqp = wc + q * 6;
    f16x8 wm[3];
    #pragma unroll
    for (int kw = 0; kw < 3; ++kw) {
        #pragma unroll
        for (int j = 0; j < 8; ++j) {
            const int ci = j & 3, jj = j >> 2;
            float v = (ci < 3) ? wqp[ci * 27 + 3 * jj + kw] : 0.f;
            wm[kw][j] = (f16)v;
        }
    }
    f16x8 wg = {};
    if (q == 0) {
        #pragma unroll
        for (int j = 0; j < 8; ++j) {
            const int ci = j & 3, kw = j >> 2;
            if (ci < 3) wg[j] = (f16)wc[ci * 27 + 24 + kw];
        }
    } else if (q == 1) {
        #pragma unroll
        for (int j = 0; j < 3; ++j) wg[j] = (f16)wc[j * 27 + 26];
    }
    const float4 bv = *(const float4*)(bias + q * 4);   // couts 4q+0..3

    // ---- Stage x[b,:,d0..d0+5,0..29,0..31] -> cin-interleaved f16 LDS ----
    for (int i = tid; i < 1440; i += 256) {              // 6 dd * 30 hh * 8 wq
        int wqd = i & 7;
        int r   = i >> 3;
        int hh  = r % 30;
        int dd  = r / 30;
        const float* px = x + ((size_t)b * 48 + (d0 + dd)) * 1024 + hh * 32 + wqd * 4;
        float4 a0 = *(const float4*)(px);
        float4 a1 = *(const float4*)(px + 16384);
        float4 a2 = *(const float4*)(px + 32768);
        f16x8 p0, p1;
        p0[0] = (f16)a0.x; p0[1] = (f16)a1.x; p0[2] = (f16)a2.x; p0[3] = (f16)0.f;
        p0[4] = (f16)a0.y; p0[5] = (f16)a1.y; p0[6] = (f16)a2.y; p0[7] = (f16)0.f;
        p1[0] = (f16)a0.z; p1[1] = (f16)a1.z; p1[2] = (f16)a2.z; p1[3] = (f16)0.f;
        p1[4] = (f16)a0.w; p1[5] = (f16)a1.w; p1[6] = (f16)a2.w; p1[7] = (f16)0.f;
        f16* dst = xs + ((dd * 30 + hh) * 36 + wqd * 4) * 4;
        *(f16x8*)(dst)     = p0;
        *(f16x8*)(dst + 8) = p1;
    }

    // per-lane B-read invariants
    const int g0   = q * 2;
    const int off1 = (g0 / 3) * PLANEU + (g0 % 3) * ROWU;
    const int off2 = ((g0 + 1) / 3) * PLANEU + ((g0 + 1) % 3) * ROWU;
    const int hl = col >> 2, wl = col & 3;
    const int spat  = hl * ROWU + wl * 4;
    const int g8sel = (q == 0) ? 0 : 8;

    __syncthreads();   // the only barrier

    // ---- cell pairs: (c, c+4); wave0's 13th cell pairs with itself ----
    for (int c = wave; c < 49; c += 8) {
        const int cA = c;
        int cB = c + 4; if (cB > 48) cB = cA;
        const f16* baseA = xs + (cA / 7) * 4 * ROWU + (cA % 7) * 16 + spat;
        const f16* baseB = xs + (cB / 7) * 4 * ROWU + (cB % 7) * 16 + spat;

        f32x4 pmA = {0.f, 0.f, 0.f, 0.f};
        f32x4 pmB = {0.f, 0.f, 0.f, 0.f};

        #pragma unroll
        for (int d = 0; d < 4; ++d) {
            CELLD(baseA + d * PLANEU, pmA);
            CELLD(baseB + d * PLANEU, pmB);
        }

        // pool over the 16 positions of each cell (xor 1,2,4,8 within col group)
        #pragma unroll
        for (int m = 1; m <= 8; m <<= 1) {
            pmA[0] = fmaxf(pmA[0], __shfl_xor(pmA[0], m));
            pmA[1] = fmaxf(pmA[1], __shfl_xor(pmA[1], m));
            pmA[2] = fmaxf(pmA[2], __shfl_xor(pmA[2], m));
            pmA[3] = fmaxf(pmA[3], __shfl_xor(pmA[3], m));
            pmB[0] = fmaxf(pmB[0], __shfl_xor(pmB[0], m));
            pmB[1] = fmaxf(pmB[1], __shfl_xor(pmB[1], m));
            pmB[2] = fmaxf(pmB[2], __shfl_xor(pmB[2], m));
            pmB[3] = fmaxf(pmB[3], __shfl_xor(pmB[3], m));
        }

        if (col == 0) {
            float* poA = out + ((size_t)b * COUT + q * 4) * 147 + pd * 49 + cA;
            poA[0]   = pmA[0];
            poA[147] = pmA[1];
            poA[294] = pmA[2];
            poA[441] = pmA[3];
            if (cB != cA) {
                float* poB = out + ((size_t)b * COUT + q * 4) * 147 + pd * 49 + cB;
                poB[0]   = pmB[0];
                poB[147] = pmB[1];
                poB[294] = pmB[2];
                poB[441] = pmB[3];
            }
        }
    }
}

extern "C" void kernel_launch(void* const* d_in, const int* in_sizes, int n_in,
                              void* d_out, int out_size, void* d_ws, size_t ws_size,
                              hipStream_t stream) {
    const float* x    = (const float*)d_in[0];
    const float* W    = (const float*)d_in[1];
    const float* bias = (const float*)d_in[2];
    float* out = (float*)d_out;

    conv_sm_pool_mfma<<<BATCH * 3, 256, 0, stream>>>(x, W, bias, out);
}